// Round 1
// baseline (47.782 us; speedup 1.0000x reference)
//
#include <hip/hip_runtime.h>
#include <math.h>

#define BATCH 8192
#define NLEN 4096
#define THREADS 256
#define PER_THREAD (NLEN / THREADS)  // 16

// ---------------------------------------------------------------------------
// Kernel 1: one block per row. Each thread owns 16 contiguous elements
// (float4-loaded). Computes masked sum/sumsq/cnt and compacted-neighbor
// diffs (within-chunk sequential; cross-chunk boundary diff via LDS
// scan-back to the nearest preceding chunk with a valid element).
// ---------------------------------------------------------------------------
__global__ __launch_bounds__(THREADS) void hrv_feats_kernel(
    const float* __restrict__ rr, float* __restrict__ feats) {
    __shared__ float sh_last[THREADS];
    __shared__ unsigned char sh_has[THREADS];
    __shared__ double sh_sum[4], sh_sumsq[4], sh_sumd2[4];
    __shared__ int sh_cnt[4], sh_nn50[4];

    const int row = blockIdx.x;
    const int t = threadIdx.x;
    const float* r = rr + (size_t)row * NLEN + t * PER_THREAD;

    float x[PER_THREAD];
    float4* xv = reinterpret_cast<float4*>(x);
    const float4* rv = reinterpret_cast<const float4*>(r);
#pragma unroll
    for (int i = 0; i < PER_THREAD / 4; ++i) xv[i] = rv[i];

    float sum = 0.f, sumsq = 0.f, sumd2 = 0.f;
    int cnt = 0, nn50 = 0;
    float first = 0.f, last = 0.f;
    int has = 0;
#pragma unroll
    for (int i = 0; i < PER_THREAD; ++i) {
        float v = x[i];
        if (v > 0.f) {
            sum += v;
            sumsq += v * v;
            ++cnt;
            if (has) {
                float d = v - last;  // same f32 subtraction as reference
                sumd2 += d * d;
                nn50 += (fabsf(d) > 0.05f) ? 1 : 0;
            } else {
                first = v;
                has = 1;
            }
            last = v;
        }
    }
    sh_last[t] = last;
    sh_has[t] = (unsigned char)has;
    __syncthreads();
    // boundary diff: my first valid vs last valid of nearest preceding
    // chunk that has one (typically j == t-1; gap prob ~0.3^16)
    if (has && t > 0) {
        for (int j = t - 1; j >= 0; --j) {
            if (sh_has[j]) {
                float d = first - sh_last[j];
                sumd2 += d * d;
                nn50 += (fabsf(d) > 0.05f) ? 1 : 0;
                break;
            }
        }
    }

    // block reduction (doubles for the sums: the downstream batch-norm
    // divides by cross-row stds ~0.004, amplifying per-row errors x200)
    double dsum = sum, dsumsq = sumsq, dsumd2 = sumd2;
    int icnt = cnt, inn = nn50;
#pragma unroll
    for (int off = 32; off > 0; off >>= 1) {
        dsum += __shfl_down(dsum, off, 64);
        dsumsq += __shfl_down(dsumsq, off, 64);
        dsumd2 += __shfl_down(dsumd2, off, 64);
        icnt += __shfl_down(icnt, off, 64);
        inn += __shfl_down(inn, off, 64);
    }
    const int wave = t >> 6;
    if ((t & 63) == 0) {
        sh_sum[wave] = dsum;
        sh_sumsq[wave] = dsumsq;
        sh_sumd2[wave] = dsumd2;
        sh_cnt[wave] = icnt;
        sh_nn50[wave] = inn;
    }
    __syncthreads();
    if (t == 0) {
        double S = 0, S2 = 0, D2 = 0;
        int C = 0, NN = 0;
        for (int w = 0; w < 4; ++w) {
            S += sh_sum[w];
            S2 += sh_sumsq[w];
            D2 += sh_sumd2[w];
            C += sh_cnt[w];
            NN += sh_nn50[w];
        }
        const float cntf = (float)C;
        const float denom_m = fmaxf(cntf, 1.f);
        const float mean = (float)(S / (double)denom_m);
        // sum((x-mean)^2) over valid == sumsq - cnt*mean^2 (exact identity
        // when mean = sum/cnt; both 0 when cnt == 0)
        const float varsum = (float)(S2 - (double)C * (double)mean * (double)mean);
        const float denom_v = fmaxf(cntf - 1.f, 1.f);
        const float sdnn = sqrtf(fmaxf(varsum / denom_v, 0.f));
        const float rmssd = sqrtf(fmaxf((float)(D2 / (double)denom_v), 0.f));
        const float pnn50 = (float)NN / denom_v;
        const float hr = 60.f / fmaxf(mean, 1e-12f);
        const float cv = sdnn / fmaxf(mean, 1e-12f);
        float f0 = mean, f1 = sdnn, f2 = rmssd, f3 = pnn50, f4 = hr, f5 = cv;
        if (C <= 1) { f0 = f1 = f2 = f3 = f4 = f5 = 0.f; }
        float* o = feats + row * 6;
        o[0] = f0; o[1] = f1; o[2] = f2;
        o[3] = f3; o[4] = f4; o[5] = f5;
    }
}

// ---------------------------------------------------------------------------
// Kernel 2: per-column mean / std(ddof=1) / max over B rows. Double
// accumulators: (sumsq - B*mean^2) cancels ~5 significant digits here.
// ---------------------------------------------------------------------------
__global__ __launch_bounds__(THREADS) void col_stats_kernel(
    const float* __restrict__ feats, float* __restrict__ stats) {
    __shared__ double sh_s[4], sh_s2[4];
    __shared__ float sh_m[4];
    const int col = blockIdx.x;
    const int t = threadIdx.x;
    double s = 0.0, s2 = 0.0;
    float mx = -INFINITY;
    for (int i = t; i < BATCH; i += THREADS) {
        float f = feats[i * 6 + col];
        s += (double)f;
        s2 += (double)f * (double)f;
        mx = fmaxf(mx, f);
    }
#pragma unroll
    for (int off = 32; off > 0; off >>= 1) {
        s += __shfl_down(s, off, 64);
        s2 += __shfl_down(s2, off, 64);
        mx = fmaxf(mx, __shfl_down(mx, off, 64));
    }
    const int wave = t >> 6;
    if ((t & 63) == 0) { sh_s[wave] = s; sh_s2[wave] = s2; sh_m[wave] = mx; }
    __syncthreads();
    if (t == 0) {
        double S = 0, S2 = 0;
        float M = -INFINITY;
        for (int w = 0; w < 4; ++w) {
            S += sh_s[w];
            S2 += sh_s2[w];
            M = fmaxf(M, sh_m[w]);
        }
        const double meanb = S / (double)BATCH;
        double var = (S2 - (double)BATCH * meanb * meanb) / (double)(BATCH - 1);
        if (var < 0.0) var = 0.0;
        stats[col] = (float)meanb;
        stats[6 + col] = (float)sqrt(var);
        stats[12 + col] = M;
    }
}

// ---------------------------------------------------------------------------
// Kernel 3: normalize feats (where col_max > 0) + 6->16 ReLU -> 32 MLP.
// One thread per row; coalesced-ish float4 output writes.
// ---------------------------------------------------------------------------
__global__ __launch_bounds__(THREADS) void mlp_kernel(
    const float* __restrict__ feats, const float* __restrict__ stats,
    const float* __restrict__ w1, const float* __restrict__ b1,
    const float* __restrict__ w2, const float* __restrict__ b2,
    float* __restrict__ out) {
    const int tid = blockIdx.x * blockDim.x + threadIdx.x;
    if (tid >= BATCH) return;
    float f[6];
#pragma unroll
    for (int c = 0; c < 6; ++c) {
        float v = feats[tid * 6 + c];
        if (stats[12 + c] > 0.f) v = (v - stats[c]) / (stats[6 + c] + 1e-8f);
        f[c] = v;
    }
    float h[16];
#pragma unroll
    for (int j = 0; j < 16; ++j) {
        float a = b1[j];
#pragma unroll
        for (int c = 0; c < 6; ++c) a = fmaf(f[c], w1[c * 16 + j], a);
        h[j] = fmaxf(a, 0.f);
    }
    float o[32];
#pragma unroll
    for (int k = 0; k < 32; ++k) o[k] = b2[k];
#pragma unroll
    for (int j = 0; j < 16; ++j) {
        const float hj = h[j];
#pragma unroll
        for (int k = 0; k < 32; ++k) o[k] = fmaf(hj, w2[j * 32 + k], o[k]);
    }
    float4* ov = reinterpret_cast<float4*>(out + (size_t)tid * 32);
    const float4* op = reinterpret_cast<const float4*>(o);
#pragma unroll
    for (int i = 0; i < 8; ++i) ov[i] = op[i];
}

extern "C" void kernel_launch(void* const* d_in, const int* in_sizes, int n_in,
                              void* d_out, int out_size, void* d_ws, size_t ws_size,
                              hipStream_t stream) {
    const float* rr = (const float*)d_in[0];
    const float* w1 = (const float*)d_in[1];
    const float* b1 = (const float*)d_in[2];
    const float* w2 = (const float*)d_in[3];
    const float* b2 = (const float*)d_in[4];
    float* out = (float*)d_out;
    float* feats = (float*)d_ws;            // BATCH*6 floats = 192 KiB
    float* stats = feats + BATCH * 6;       // 18 floats (mean[6], std[6], max[6])

    hrv_feats_kernel<<<BATCH, THREADS, 0, stream>>>(rr, feats);
    col_stats_kernel<<<6, THREADS, 0, stream>>>(feats, stats);
    mlp_kernel<<<BATCH / THREADS, THREADS, 0, stream>>>(feats, stats, w1, b1, w2, b2, out);
}

// Round 2
// 41.590 us; speedup vs baseline: 1.1489x; 1.1489x over previous
//
#include <hip/hip_runtime.h>
#include <math.h>

#define BATCH 8192
#define NLEN 4096

// ---------------------------------------------------------------------------
// Kernel 1: ONE WAVE PER ROW (4 rows per 256-thread block). Lane l owns the
// contiguous 64-element chunk [l*64, l*64+64). No LDS, no __syncthreads.
// Cross-lane compacted-diff boundary via __ballot + nearest-lower-set-bit +
// one variable-lane shuffle. f32 per-16-elem partial sums folded into double
// accumulators (batch-norm downstream divides by col stds ~0.005, amplifying
// per-row error ~200x; this scheme passed with 10x margin).
// ---------------------------------------------------------------------------
__global__ __launch_bounds__(256) void hrv_feats_kernel(
    const float* __restrict__ rr, float* __restrict__ feats) {
    const int lane = threadIdx.x & 63;
    const int wid = threadIdx.x >> 6;
    const int row = blockIdx.x * 4 + wid;
    const float* r = rr + (size_t)row * NLEN + lane * 64;

    double dsum = 0.0, dsumsq = 0.0, dsumd2 = 0.0;
    int cnt = 0, nn50 = 0, has = 0;
    float first = 0.f, last = 0.f;

    float x[32];
    float4* xv = reinterpret_cast<float4*>(x);
    const float4* rv = reinterpret_cast<const float4*>(r);

#pragma unroll
    for (int half = 0; half < 2; ++half) {
#pragma unroll
        for (int i = 0; i < 8; ++i) xv[i] = rv[half * 8 + i];
#pragma unroll
        for (int c = 0; c < 2; ++c) {
            float s = 0.f, s2 = 0.f, d2 = 0.f;
#pragma unroll
            for (int i = 0; i < 16; ++i) {
                float v = x[c * 16 + i];
                if (v > 0.f) {
                    s += v;
                    s2 += v * v;
                    ++cnt;
                    if (has) {
                        float d = v - last;  // same f32 sub as reference
                        d2 += d * d;
                        nn50 += (fabsf(d) > 0.05f) ? 1 : 0;
                    } else {
                        first = v;
                        has = 1;
                    }
                    last = v;
                }
            }
            dsum += s;
            dsumsq += s2;
            dsumd2 += d2;
        }
    }

    // boundary diff: my first valid vs last valid of nearest lower lane
    // that has a valid element (compacted-sequence adjacency)
    unsigned long long m = __ballot(has != 0);
    unsigned long long pm = (lane == 0) ? 0ull : (m & ((1ull << lane) - 1ull));
    int j = 63 - __clzll(pm | 1ull);  // j==0 also when pm=={0,1}; guarded below
    float lastj = __shfl(last, j, 64);
    if (has && pm) {
        float d = first - lastj;
        dsumd2 += (double)(d * d);
        nn50 += (fabsf(d) > 0.05f) ? 1 : 0;
    }

    // wave butterfly reduction (3 doubles + 2 ints)
#pragma unroll
    for (int off = 32; off; off >>= 1) {
        dsum += __shfl_down(dsum, off, 64);
        dsumsq += __shfl_down(dsumsq, off, 64);
        dsumd2 += __shfl_down(dsumd2, off, 64);
        cnt += __shfl_down(cnt, off, 64);
        nn50 += __shfl_down(nn50, off, 64);
    }

    if (lane == 0) {
        const float cntf = (float)cnt;
        const float denom_m = fmaxf(cntf, 1.f);
        const float mean = (float)(dsum / (double)denom_m);
        const float varsum = (float)(dsumsq - (double)cnt * (double)mean * (double)mean);
        const float denom_v = fmaxf(cntf - 1.f, 1.f);
        const float sdnn = sqrtf(fmaxf(varsum / denom_v, 0.f));
        const float rmssd = sqrtf(fmaxf((float)(dsumd2 / (double)denom_v), 0.f));
        const float pnn50 = (float)nn50 / denom_v;
        const float hr = 60.f / fmaxf(mean, 1e-12f);
        const float cv = sdnn / fmaxf(mean, 1e-12f);
        float f0 = mean, f1 = sdnn, f2 = rmssd, f3 = pnn50, f4 = hr, f5 = cv;
        if (cnt <= 1) { f0 = f1 = f2 = f3 = f4 = f5 = 0.f; }
        float* o = feats + row * 6;
        o[0] = f0; o[1] = f1; o[2] = f2;
        o[3] = f3; o[4] = f4; o[5] = f5;
    }
}

// ---------------------------------------------------------------------------
// Kernel 2 (fused col-stats + MLP): 32 blocks x 256 threads. Each block
// REDUNDANTLY computes the column mean/std/max over all 8192 rows (feats is
// 192 KiB, L2-resident; 32x redundancy = 6 MB of L2 reads ~ 0.2 us), then
// applies normalize + 6->16 ReLU -> 32 MLP to its own 256 rows. Identical
// deterministic stats in every block; kills one kernel launch.
// ---------------------------------------------------------------------------
__global__ __launch_bounds__(256) void stats_mlp_kernel(
    const float* __restrict__ feats,
    const float* __restrict__ w1, const float* __restrict__ b1,
    const float* __restrict__ w2, const float* __restrict__ b2,
    float* __restrict__ out) {
    __shared__ double sh_s[4][6], sh_s2[4][6];
    __shared__ float sh_m[4][6];
    __shared__ float sh_stats[18];  // mean[6], std[6], max[6]

    const int t = threadIdx.x;
    double s[6] = {0, 0, 0, 0, 0, 0};
    double s2[6] = {0, 0, 0, 0, 0, 0};
    float mx[6] = {-INFINITY, -INFINITY, -INFINITY, -INFINITY, -INFINITY, -INFINITY};

#pragma unroll 4
    for (int i = t; i < BATCH; i += 256) {
        const float* fp = feats + i * 6;
#pragma unroll
        for (int c = 0; c < 6; ++c) {
            float f = fp[c];
            s[c] += (double)f;
            s2[c] += (double)f * (double)f;
            mx[c] = fmaxf(mx[c], f);
        }
    }
#pragma unroll
    for (int off = 32; off; off >>= 1) {
#pragma unroll
        for (int c = 0; c < 6; ++c) {
            s[c] += __shfl_down(s[c], off, 64);
            s2[c] += __shfl_down(s2[c], off, 64);
            mx[c] = fmaxf(mx[c], __shfl_down(mx[c], off, 64));
        }
    }
    if ((t & 63) == 0) {
        const int w = t >> 6;
#pragma unroll
        for (int c = 0; c < 6; ++c) {
            sh_s[w][c] = s[c];
            sh_s2[w][c] = s2[c];
            sh_m[w][c] = mx[c];
        }
    }
    __syncthreads();
    if (t < 6) {
        double S = 0, S2 = 0;
        float M = -INFINITY;
        for (int w = 0; w < 4; ++w) {
            S += sh_s[w][t];
            S2 += sh_s2[w][t];
            M = fmaxf(M, sh_m[w][t]);
        }
        const double meanb = S / (double)BATCH;
        double var = (S2 - (double)BATCH * meanb * meanb) / (double)(BATCH - 1);
        if (var < 0.0) var = 0.0;
        sh_stats[t] = (float)meanb;
        sh_stats[6 + t] = (float)sqrt(var);
        sh_stats[12 + t] = M;
    }
    __syncthreads();

    const int row = blockIdx.x * 256 + t;
    const float* fp = feats + row * 6;
    float f[6];
#pragma unroll
    for (int c = 0; c < 6; ++c) {
        float v = fp[c];
        if (sh_stats[12 + c] > 0.f) v = (v - sh_stats[c]) / (sh_stats[6 + c] + 1e-8f);
        f[c] = v;
    }
    float h[16];
#pragma unroll
    for (int j = 0; j < 16; ++j) {
        float a = b1[j];
#pragma unroll
        for (int c = 0; c < 6; ++c) a = fmaf(f[c], w1[c * 16 + j], a);
        h[j] = fmaxf(a, 0.f);
    }
    float o[32];
#pragma unroll
    for (int k = 0; k < 32; ++k) o[k] = b2[k];
#pragma unroll
    for (int j = 0; j < 16; ++j) {
        const float hj = h[j];
#pragma unroll
        for (int k = 0; k < 32; ++k) o[k] = fmaf(hj, w2[j * 32 + k], o[k]);
    }
    float4* ov = reinterpret_cast<float4*>(out + (size_t)row * 32);
    const float4* op = reinterpret_cast<const float4*>(o);
#pragma unroll
    for (int i = 0; i < 8; ++i) ov[i] = op[i];
}

extern "C" void kernel_launch(void* const* d_in, const int* in_sizes, int n_in,
                              void* d_out, int out_size, void* d_ws, size_t ws_size,
                              hipStream_t stream) {
    const float* rr = (const float*)d_in[0];
    const float* w1 = (const float*)d_in[1];
    const float* b1 = (const float*)d_in[2];
    const float* w2 = (const float*)d_in[3];
    const float* b2 = (const float*)d_in[4];
    float* out = (float*)d_out;
    float* feats = (float*)d_ws;  // BATCH*6 floats = 192 KiB

    hrv_feats_kernel<<<BATCH / 4, 256, 0, stream>>>(rr, feats);
    stats_mlp_kernel<<<BATCH / 256, 256, 0, stream>>>(feats, w1, b1, w2, b2, out);
}